// Round 9
// baseline (209.329 us; speedup 1.0000x reference)
//
#include <hip/hip_runtime.h>
#include <hip/hip_bf16.h>
#include <math.h>

#define TN 1000
#define SPD_EPS 1e-3f

// logm Taylor params: t = (S - M0*I)/R0, spectrum certified in [0.35,1.93]
#define M0 1.16f
#define R0 0.86f
#define BETA 0.7413793103f   // R0/M0

typedef float f32x16 __attribute__((ext_vector_type(16)));
typedef short bf16x8 __attribute__((ext_vector_type(8)));

// W21 = W2 @ W1  : (32x64)@(64x128) -> 32x128
__global__ void w21_kernel(const float* __restrict__ W2, const float* __restrict__ W1,
                           float* __restrict__ W21) {
  int idx = blockIdx.x * 256 + threadIdx.x;
  if (idx < 32 * 128) {
    int c = idx >> 7, k = idx & 127;
    float acc = 0.f;
#pragma unroll 8
    for (int m = 0; m < 64; ++m) acc += W2[c * 64 + m] * W1[m * 128 + k];
    W21[idx] = acc;
  }
}

__device__ __forceinline__ int tix(int r, int c) {  // r <= c, 4x4 upper-tri tile index
  return r * 4 - (r * (r - 1)) / 2 + (c - r);
}

// One block (4 waves) per batch. 4 phases of t-chunk 256: each row's chunk is
// ONE 1KB-contiguous dwordx4 wave-instruction (DRAM page-friendly), converted
// to bf16 into a single 64KB LDS buffer [128][256] with 8B-granule XOR swizzle
// (byte ^= (row&15)<<3) so column fragment reads don't bank-serialize.
// fp32 column sums in 32 static registers. Epilogue: Latin merge of the 10
// upper-tri 32x32 MFMA Gram tiles, mean-sub, W21 C W21^T.
__global__ __launch_bounds__(256) void cov_kernel(const float* __restrict__ x,
                                                  const float* __restrict__ W21,
                                                  float* __restrict__ S2) {
  const int b = blockIdx.x;
  const int tid = threadIdx.x;
  const int w = tid >> 6;       // wave 0..3
  const int l = tid & 63;
  const int ch = l & 31;
  const int h = l >> 5;

  __shared__ __align__(16) char smem[65536];
  __shared__ float s_acc[128];
  ushort* ys = (ushort*)smem;           // [128][256] bf16 swizzled (main loop)
  float* Ct = (float*)smem;             // 10 tiles [32][33]   (epilogue)
  float* Pl = (float*)(smem + 42240);   // [32][130]           (epilogue)

  f32x16 acc00{}, acc01{}, acc02{}, acc03{}, acc11{}, acc12{}, acc13{},
         acc22{}, acc23{}, acc33{};
  float s_own[32];
#pragma unroll
  for (int i = 0; i < 32; ++i) s_own[i] = 0.f;

  const float* xb = x + (size_t)b * (128 * TN);
  const float4 z4 = make_float4(0.f, 0.f, 0.f, 0.f);

#define MFMAS() do {                                                         \
    acc00 = __builtin_amdgcn_mfma_f32_32x32x16_bf16(fr[0], fr[0], acc00, 0, 0, 0); \
    acc01 = __builtin_amdgcn_mfma_f32_32x32x16_bf16(fr[0], fr[1], acc01, 0, 0, 0); \
    acc02 = __builtin_amdgcn_mfma_f32_32x32x16_bf16(fr[0], fr[2], acc02, 0, 0, 0); \
    acc03 = __builtin_amdgcn_mfma_f32_32x32x16_bf16(fr[0], fr[3], acc03, 0, 0, 0); \
    acc11 = __builtin_amdgcn_mfma_f32_32x32x16_bf16(fr[1], fr[1], acc11, 0, 0, 0); \
    acc12 = __builtin_amdgcn_mfma_f32_32x32x16_bf16(fr[1], fr[2], acc12, 0, 0, 0); \
    acc13 = __builtin_amdgcn_mfma_f32_32x32x16_bf16(fr[1], fr[3], acc13, 0, 0, 0); \
    acc22 = __builtin_amdgcn_mfma_f32_32x32x16_bf16(fr[2], fr[2], acc22, 0, 0, 0); \
    acc23 = __builtin_amdgcn_mfma_f32_32x32x16_bf16(fr[2], fr[3], acc23, 0, 0, 0); \
    acc33 = __builtin_amdgcn_mfma_f32_32x32x16_bf16(fr[3], fr[3], acc33, 0, 0, 0); \
  } while (0)

  // stage one group of 8 rows: 8 x 1KB contiguous loads, sum + cvt + swizzled write
#define SGROUP(G, P, VM) do {                                                \
    float4 st[8];                                                            \
    _Pragma("unroll")                                                        \
    for (int r_ = 0; r_ < 8; ++r_) {                                         \
      const int ROW_ = 32 * w + (G) * 8 + r_;                                \
      const float* p_ = xb + (size_t)ROW_ * TN + 256 * (P) + 4 * l;          \
      st[r_] = (VM) ? *(const float4*)p_ : z4;                               \
    }                                                                        \
    _Pragma("unroll")                                                        \
    for (int r_ = 0; r_ < 8; ++r_) {                                         \
      const int ROW_ = 32 * w + (G) * 8 + r_;                                \
      const float4 v_ = st[r_];                                              \
      s_own[(G) * 8 + r_] += v_.x + v_.y + v_.z + v_.w;                      \
      union { ushort4 q; __hip_bfloat16 e[4]; } u_;                          \
      u_.e[0] = __float2bfloat16(v_.x); u_.e[1] = __float2bfloat16(v_.y);    \
      u_.e[2] = __float2bfloat16(v_.z); u_.e[3] = __float2bfloat16(v_.w);    \
      const int byo_ = (8 * l) ^ ((ROW_ & 15) << 3);                         \
      *(ushort4*)((char*)ys + ROW_ * 512 + byo_) = u_.q;                     \
    }                                                                        \
    __builtin_amdgcn_sched_barrier(0);                                       \
  } while (0)

#pragma unroll 1
  for (int p = 0; p < 4; ++p) {
    const bool vm = (256 * p + 4 * l) < TN;   // tail: phase 3 has 232 valid t
    SGROUP(0, p, vm); SGROUP(1, p, vm); SGROUP(2, p, vm); SGROUP(3, p, vm);
    __syncthreads();
    const int nsteps = (p < 3) ? 16 : 15;     // K-steps of 16 t
#pragma unroll 1
    for (int s = w; s < nsteps; s += 4) {     // K-split across waves
      bf16x8 fr[4];
#pragma unroll
      for (int r_ = 0; r_ < 4; ++r_) {
        const int ROW_ = 32 * r_ + ch;
        const int m_ = (ROW_ & 15) << 3;
        const int cb_ = s * 32 + h * 16;
        const char* base_ = (const char*)ys + ROW_ * 512;
        union { ushort4 q[2]; bf16x8 v; } u_;
        u_.q[0] = *(const ushort4*)(base_ + ((cb_) ^ m_));
        u_.q[1] = *(const ushort4*)(base_ + ((cb_ + 8) ^ m_));
        fr[r_] = u_.v;
      }
      MFMAS();
    }
    __syncthreads();
  }

  // ---- reduce column sums: rows 32w..32w+31 owned by wave w ----
#pragma unroll
  for (int i = 0; i < 32; ++i) {
    float v = s_own[i];
#pragma unroll
    for (int d = 1; d < 64; d <<= 1) v += __shfl_xor(v, d);
    if (l == 0) s_acc[32 * w + i] = v;
  }

  // ---- epilogue: ys dead; zero Ct in the same smem ----
  __syncthreads();
  for (int idx = tid; idx < 10 * 1056; idx += 256) Ct[idx] = 0.f;
  __syncthreads();

  // merge partial Grams: Latin-square (wave w -> tile (s+3w)%10)
#define ADD_T(ACC_) do {                                                     \
    float* tp_ = Ct + tlc * 1056;                                            \
    _Pragma("unroll")                                                        \
    for (int p_ = 0; p_ < 16; ++p_) {                                        \
      const int row_ = (p_ & 3) + 8 * (p_ >> 2) + 4 * h;                     \
      tp_[row_ * 33 + ch] += ACC_[p_];                                       \
    } } while (0)

#pragma unroll
  for (int s = 0; s < 10; ++s) {
    const int tlc = (s + 3 * w) % 10;
    switch (tlc) {
      case 0: ADD_T(acc00); break;
      case 1: ADD_T(acc01); break;
      case 2: ADD_T(acc02); break;
      case 3: ADD_T(acc03); break;
      case 4: ADD_T(acc11); break;
      case 5: ADD_T(acc12); break;
      case 6: ADD_T(acc13); break;
      case 7: ADD_T(acc22); break;
      case 8: ADD_T(acc23); break;
      case 9: ADD_T(acc33); break;
    }
    __syncthreads();
  }

  // mean-sub + eps, in place
  {
    const int RB[10] = {0, 0, 0, 0, 1, 1, 1, 2, 2, 3};
    const int CB[10] = {0, 1, 2, 3, 1, 2, 3, 2, 3, 3};
#pragma unroll
    for (int tl = 0; tl < 10; ++tl) {
#pragma unroll
      for (int e0 = 0; e0 < 1024; e0 += 256) {
        const int e = e0 + tid;
        const int row = e >> 5, col = e & 31;
        const int Rg = RB[tl] * 32 + row, Cg = CB[tl] * 32 + col;
        float cv = (Ct[tl * 1056 + row * 33 + col]
                    - s_acc[Rg] * s_acc[Cg] * (1.f / TN)) * (1.f / (TN - 1));
        if (Rg == Cg) cv += SPD_EPS;
        Ct[tl * 1056 + row * 33 + col] = cv;
      }
    }
  }
  __syncthreads();

  // P = W21 * C (32x128): thread owns col j, rows [rh*16, rh*16+16)
  {
    const int j = tid & 127;
    const int rh = tid >> 7;
    const int cblk = j >> 5;
    float pa[16];
#pragma unroll
    for (int i = 0; i < 16; ++i) pa[i] = 0.f;
#pragma unroll
    for (int kb = 0; kb < 4; ++kb) {
      const bool up = (kb <= cblk);
      const int t1 = up ? tix(kb, cblk) : tix(cblk, kb);
      const int base = t1 * 1056 + (up ? (j & 31) : (j & 31) * 33);
      const int stg = up ? 33 : 1;
      const float* wp = W21 + kb * 32;
#pragma unroll 1
      for (int k2 = 0; k2 < 32; ++k2) {
        const float cv = Ct[base + k2 * stg];
#pragma unroll
        for (int i = 0; i < 16; ++i)
          pa[i] = fmaf(wp[(rh * 16 + i) * 128 + k2], cv, pa[i]);
      }
    }
#pragma unroll
    for (int i = 0; i < 16; ++i) Pl[(rh * 16 + i) * 130 + j] = pa[i];
  }
  __syncthreads();

  // S2 = P * W21^T (32x32): thread owns col ch2, rows [rg*4, rg*4+4)
  {
    const int ch2 = tid & 31;
    const int rg = tid >> 5;   // 0..7
    float sc[4] = {0.f, 0.f, 0.f, 0.f};
    const float* wr = W21 + ch2 * 128;
#pragma unroll 1
    for (int k = 0; k < 128; ++k) {
      const float wv = wr[k];
#pragma unroll
      for (int i = 0; i < 4; ++i)
        sc[i] = fmaf(Pl[(rg * 4 + i) * 130 + k], wv, sc[i]);
    }
    float* So = S2 + ((size_t)b << 10);
#pragma unroll
    for (int i = 0; i < 4; ++i) So[(rg * 4 + i) * 32 + ch2] = sc[i];
  }
}

// ---------------- logm via shifted Taylor + Paterson-Stockmeyer, fused FC ----
// One wave per matrix. Lane (j=l&31, h=l>>5) owns rows [16h,16h+16) of col j.
// NOTE: i-loop unroll capped at 4 — full unroll lets the scheduler hoist all
// 128 ds_read_b128 of the loop-invariant A operand into registers -> spill.
__device__ __forceinline__ void mm_half(float* __restrict__ c,
                                        const float (* __restrict__ A)[36],
                                        const float* __restrict__ bf,
                                        const int r0) {
#pragma unroll 4
  for (int i = 0; i < 16; ++i) {
    const float4* row = (const float4*)(A[r0 + i]);
    float acc = 0.f;
#pragma unroll
    for (int kk = 0; kk < 8; ++kk) {
      const float4 r = row[kk];
      acc = fmaf(r.x, bf[4 * kk + 0], acc);
      acc = fmaf(r.y, bf[4 * kk + 1], acc);
      acc = fmaf(r.z, bf[4 * kk + 2], acc);
      acc = fmaf(r.w, bf[4 * kk + 3], acc);
    }
    c[i] = acc;
  }
}

__device__ __forceinline__ void expand32(float* __restrict__ bf,
                                         const float* __restrict__ v,
                                         const int h) {
#pragma unroll
  for (int i = 0; i < 16; ++i) {
    const float mine = v[i];
    const float other = __shfl_xor(mine, 32);
    bf[i]      = h ? other : mine;
    bf[i + 16] = h ? mine  : other;
  }
}

__global__ __launch_bounds__(64) void logm_fc_kernel(const float* __restrict__ S,
                                                     const float* __restrict__ fcw,
                                                     const float* __restrict__ fcb,
                                                     float* __restrict__ out) {
  const int b = blockIdx.x;
  const int l = threadIdx.x;
  const int j = l & 31;
  const int h = l >> 5;
  const int r0 = h << 4;
  const bool hd = ((j >> 4) == h);
  const int id = j & 15;

  __shared__ float P[6][32][36];   // P[p] = t^(p+1)
  __shared__ float a_sh[44];       // Taylor coeffs a_0..a_41

  if (l < 42) {
    if (l == 0) a_sh[0] = logf(M0);
    else a_sh[l] = ((l & 1) ? 1.f : -1.f) * __powf(BETA, (float)l) / (float)l;
  }

  float cur[16], nxt[16], acc[16], bf[32];
  const float* Sb = S + ((size_t)b << 10);
#pragma unroll
  for (int i = 0; i < 16; ++i) {
    float v = Sb[(r0 + i) * 32 + j] * (1.f / R0);
    if (hd && i == id) v -= (M0 / R0);
    cur[i] = v;
    P[0][r0 + i][j] = v;
  }
  __syncthreads();

  // powers t^2..t^6; unroll 1 so the invariant A operand isn't register-cached
#pragma unroll 1
  for (int p = 1; p < 6; ++p) {
    expand32(bf, cur, h);
    mm_half(nxt, P[0], bf, r0);
#pragma unroll
    for (int i = 0; i < 16; ++i) { cur[i] = nxt[i]; P[p][r0 + i][j] = nxt[i]; }
  }
  __syncthreads();   // powers + coeffs visible

  // ACC = B_6 = a36 I + sum_{p=1..5} a_{36+p} t^p
#pragma unroll
  for (int i = 0; i < 16; ++i) {
    float v = (hd && i == id) ? a_sh[36] : 0.f;
#pragma unroll
    for (int p = 0; p < 5; ++p)
      v = fmaf(a_sh[37 + p], P[p][r0 + i][j], v);
    acc[i] = v;
  }
  // Horner: ACC = u*ACC + B_jj, u = t^6 (LDS, never rewritten); unroll 1 (see above)
#pragma unroll 1
  for (int jj = 5; jj >= 0; --jj) {
    expand32(bf, acc, h);
    mm_half(nxt, P[5], bf, r0);
#pragma unroll
    for (int i = 0; i < 16; ++i) {
      float v = (hd && i == id) ? a_sh[6 * jj] : 0.f;
#pragma unroll
      for (int p = 0; p < 5; ++p)
        v = fmaf(a_sh[6 * jj + 1 + p], P[p][r0 + i][j], v);
      acc[i] = v + nxt[i];
    }
  }

  // fused FC: out[b][k] = fcb[k] + sum_{r,c} L[r][c] * fcw[k][r*32+c]
#pragma unroll 2
  for (int k = 0; k < 10; ++k) {
    const float* fw = fcw + (size_t)k * 1024;
    float s = 0.f;
#pragma unroll
    for (int i = 0; i < 16; ++i)
      s = fmaf(acc[i], fw[(r0 + i) * 32 + j], s);
#pragma unroll
    for (int d = 1; d < 64; d <<= 1) s += __shfl_xor(s, d);
    if (l == 0) out[b * 10 + k] = s + fcb[k];
  }
}

extern "C" void kernel_launch(void* const* d_in, const int* in_sizes, int n_in,
                              void* d_out, int out_size, void* d_ws, size_t ws_size,
                              hipStream_t stream) {
  const float* x   = (const float*)d_in[0];
  const float* W1  = (const float*)d_in[1];
  const float* W2  = (const float*)d_in[2];
  const float* fcw = (const float*)d_in[3];
  const float* fcb = (const float*)d_in[4];
  float* out = (float*)d_out;
  char* ws = (char*)d_ws;
  float* W21 = (float*)ws;              // 16 KB
  float* S2  = (float*)(ws + 65536);    // 2 MB

  w21_kernel<<<16, 256, 0, stream>>>(W2, W1, W21);
  cov_kernel<<<512, 256, 0, stream>>>(x, W21, S2);
  logm_fc_kernel<<<512, 64, 0, stream>>>(S2, fcw, fcb, out);
}

// Round 10
// 184.393 us; speedup vs baseline: 1.1352x; 1.1352x over previous
//
#include <hip/hip_runtime.h>
#include <hip/hip_bf16.h>
#include <math.h>

#define TN 1000
#define SPD_EPS 1e-3f

// logm Taylor params: t = (S - M0*I)/R0, spectrum certified in [0.35,1.93]
#define M0 1.16f
#define R0 0.86f
#define BETA 0.7413793103f   // R0/M0

typedef float f32x16 __attribute__((ext_vector_type(16)));
typedef short bf16x8 __attribute__((ext_vector_type(8)));

// W21 = W2 @ W1  : (32x64)@(64x128) -> 32x128
__global__ void w21_kernel(const float* __restrict__ W2, const float* __restrict__ W1,
                           float* __restrict__ W21) {
  int idx = blockIdx.x * 256 + threadIdx.x;
  if (idx < 32 * 128) {
    int c = idx >> 7, k = idx & 127;
    float acc = 0.f;
#pragma unroll 8
    for (int m = 0; m < 64; ++m) acc += W2[c * 64 + m] * W1[m * 128 + k];
    W21[idx] = acc;
  }
}

// One block = (batch, t-half of 512). Wave w owns Gram tile-column w:
// accs = C_{r,w} r=0..3 (full, not upper-tri) -> NO cross-wave merge.
// Stage x bf16 into double-buffered LDS (R7's coalesced 256B row-runs).
// Epilogue: P = W21*G_half (per-wave cols), Q = P*W21^T + t_half = W21*s_half
// -> ws. Mean-sub/eps deferred to logm prologue (exact: halves combine there).
__global__ __launch_bounds__(256, 3) void cov_kernel(const float* __restrict__ x,
                                                     const float* __restrict__ W21g,
                                                     float* __restrict__ Qt) {
  const int bid = blockIdx.x;
  const int b = bid >> 1, half = bid & 1;
  const int tid = threadIdx.x;
  const int w = tid >> 6;       // wave 0..3 = tile column
  const int l = tid & 63;
  const int ch = l & 31;
  const int h = l >> 5;
  const int g = l & 15;         // float4 index within 64-t row-run
  const int rr = (l >> 4) & 3;  // row within 4-row group

  __shared__ ushort ys[2][128][68];   // 34816B staging (dead in epilogue)
  __shared__ float s_acc[128];
  float* W21l = (float*)ys;                   // [32][128] 16384B (epilogue)
  float* Pl   = (float*)((char*)ys + 16384);  // [32][132] 16896B (epilogue)

  if (tid < 128) s_acc[tid] = 0.f;

  f32x16 a0{}, a1{}, a2{}, a3{};
  float4 st[8];
  bf16x8 fr[4], bw;
  const float* xb = x + (size_t)b * (128 * TN) + half * 512;
  const float4 z4 = make_float4(0.f, 0.f, 0.f, 0.f);

#define CLOAD(TT) do {                                                       \
    const bool v_ = (half * 512 + (TT) * 64 + 4 * g) < TN;                   \
    _Pragma("unroll")                                                        \
    for (int rg_ = 0; rg_ < 8; ++rg_) {                                      \
      const int R_ = 32 * w + 4 * rg_ + rr;                                  \
      st[rg_] = v_ ? *(const float4*)(xb + (size_t)R_ * TN + (TT) * 64 + 4 * g) \
                   : z4;                                                     \
    } } while (0)

#define CSTORE(BUF) do {                                                     \
    _Pragma("unroll")                                                        \
    for (int rg_ = 0; rg_ < 8; ++rg_) {                                      \
      const int R_ = 32 * w + 4 * rg_ + rr;                                  \
      const float4 v_ = st[rg_];                                             \
      float sm_ = v_.x + v_.y + v_.z + v_.w;                                 \
      sm_ += __shfl_xor(sm_, 1); sm_ += __shfl_xor(sm_, 2);                  \
      sm_ += __shfl_xor(sm_, 4); sm_ += __shfl_xor(sm_, 8);                  \
      if (g == 0) s_acc[R_] += sm_;                                          \
      union { ushort4 q; __hip_bfloat16 e[4]; } u_;                          \
      u_.e[0] = __float2bfloat16(v_.x); u_.e[1] = __float2bfloat16(v_.y);    \
      u_.e[2] = __float2bfloat16(v_.z); u_.e[3] = __float2bfloat16(v_.w);    \
      *(ushort4*)&ys[BUF][R_][4 * g] = u_.q;                                 \
    } } while (0)

  // per K-step: A-frags for row-blocks 0..3 + B-frag = own column block w
#define CCONSUME(BUF) do {                                                   \
    _Pragma("unroll")                                                        \
    for (int s_ = 0; s_ < 4; ++s_) {                                         \
      _Pragma("unroll")                                                      \
      for (int r_ = 0; r_ < 4; ++r_) {                                       \
        const ushort* p_ = &ys[BUF][32 * r_ + ch][16 * s_ + 8 * h];          \
        union { ushort4 q[2]; bf16x8 v; } u_;                                \
        u_.q[0] = *(const ushort4*)p_; u_.q[1] = *(const ushort4*)(p_ + 4);  \
        fr[r_] = u_.v;                                                       \
      }                                                                      \
      { const ushort* pb_ = &ys[BUF][32 * w + ch][16 * s_ + 8 * h];          \
        union { ushort4 q[2]; bf16x8 v; } ub_;                               \
        ub_.q[0] = *(const ushort4*)pb_;                                     \
        ub_.q[1] = *(const ushort4*)(pb_ + 4);                               \
        bw = ub_.v; }                                                        \
      a0 = __builtin_amdgcn_mfma_f32_32x32x16_bf16(fr[0], bw, a0, 0, 0, 0);  \
      a1 = __builtin_amdgcn_mfma_f32_32x32x16_bf16(fr[1], bw, a1, 0, 0, 0);  \
      a2 = __builtin_amdgcn_mfma_f32_32x32x16_bf16(fr[2], bw, a2, 0, 0, 0);  \
      a3 = __builtin_amdgcn_mfma_f32_32x32x16_bf16(fr[3], bw, a3, 0, 0, 0);  \
    } } while (0)

  CLOAD(0);
  __syncthreads();             // s_acc zero visible
  CSTORE(0);
  __syncthreads();
#pragma unroll 1
  for (int tt = 0; tt < 8; ++tt) {
    if (tt < 7) CLOAD(tt + 1);       // next tile's loads fly during consume
    CCONSUME(tt & 1);
    if (tt < 7) CSTORE((tt + 1) & 1);
    __syncthreads();
  }

  // ---- epilogue: staging dead; W21 -> LDS ----
  for (int idx = tid; idx < 1024; idx += 256)
    ((float4*)W21l)[idx] = ((const float4*)W21g)[idx];
  __syncthreads();   // W21l + final s_acc visible

  // P[:, cols in block w] = sum_r W21[:, block r] * C_{r,w} (raw Gram)
  float pa[32];
#pragma unroll
  for (int i = 0; i < 32; ++i) pa[i] = 0.f;

#define EPIR(RV, A_) do {                                                    \
    float cv[32];                                                            \
    _Pragma("unroll")                                                        \
    for (int p_ = 0; p_ < 16; ++p_) {                                        \
      const int K0 = (p_ & 3) + 8 * (p_ >> 2);                               \
      const float o_ = A_[p_];                                               \
      const float x_ = __shfl_xor(o_, 32);                                   \
      cv[K0]     = h ? x_ : o_;                                              \
      cv[K0 + 4] = h ? o_ : x_;                                              \
    }                                                                        \
    _Pragma("unroll 4")                                                      \
    for (int i_ = 0; i_ < 32; ++i_) {                                        \
      float ac_ = 0.f;                                                       \
      _Pragma("unroll")                                                      \
      for (int kq_ = 0; kq_ < 8; ++kq_) {                                    \
        const float4 wv_ = *(const float4*)&W21l[i_ * 128 + 32 * (RV) + 4 * kq_]; \
        ac_ = fmaf(wv_.x, cv[4 * kq_ + 0], ac_);                             \
        ac_ = fmaf(wv_.y, cv[4 * kq_ + 1], ac_);                             \
        ac_ = fmaf(wv_.z, cv[4 * kq_ + 2], ac_);                             \
        ac_ = fmaf(wv_.w, cv[4 * kq_ + 3], ac_);                             \
      }                                                                      \
      pa[i_] += ac_;                                                         \
    } } while (0)

  EPIR(0, a0); EPIR(1, a1); EPIR(2, a2); EPIR(3, a3);
#pragma unroll
  for (int i = 0; i < 32; ++i) Pl[i * 132 + 32 * w + ch] = pa[i];
  __syncthreads();

  // Q = P * W21^T (32x32) and t_half = W21 * s_half -> ws
  {
    const int j2 = tid & 31;
    const int rq = tid >> 5;   // 0..7 -> rows 4rq..4rq+3
    float sc[4] = {0.f, 0.f, 0.f, 0.f};
    const float* wr = W21g + j2 * 128;
#pragma unroll 1
    for (int k = 0; k < 128; ++k) {
      const float wv = wr[k];
#pragma unroll
      for (int i = 0; i < 4; ++i)
        sc[i] = fmaf(Pl[(4 * rq + i) * 132 + k], wv, sc[i]);
    }
    float* Qb = Qt + (size_t)bid * 1056;
#pragma unroll
    for (int i = 0; i < 4; ++i) Qb[(4 * rq + i) * 32 + j2] = sc[i];
    if (tid < 32) {
      float tv = 0.f;
      const float* wr2 = W21g + tid * 128;
#pragma unroll 4
      for (int k = 0; k < 128; ++k) tv = fmaf(wr2[k], s_acc[k], tv);
      Qb[1024 + tid] = tv;
    }
  }
}

// ---------------- logm via shifted Taylor + Paterson-Stockmeyer, fused FC ----
// Prologue combines the two half-Grams: S2 = ((Q1+Q2) - t t^T/T)/(T-1) + eps I.
// One wave per matrix. Lane (j=l&31, h=l>>5) owns rows [16h,16h+16) of col j.
// NOTE: i-loop unroll capped at 4 — full unroll lets the scheduler hoist all
// 128 ds_read_b128 of the loop-invariant A operand into registers -> spill.
__device__ __forceinline__ void mm_half(float* __restrict__ c,
                                        const float (* __restrict__ A)[36],
                                        const float* __restrict__ bf,
                                        const int r0) {
#pragma unroll 4
  for (int i = 0; i < 16; ++i) {
    const float4* row = (const float4*)(A[r0 + i]);
    float acc = 0.f;
#pragma unroll
    for (int kk = 0; kk < 8; ++kk) {
      const float4 r = row[kk];
      acc = fmaf(r.x, bf[4 * kk + 0], acc);
      acc = fmaf(r.y, bf[4 * kk + 1], acc);
      acc = fmaf(r.z, bf[4 * kk + 2], acc);
      acc = fmaf(r.w, bf[4 * kk + 3], acc);
    }
    c[i] = acc;
  }
}

__device__ __forceinline__ void expand32(float* __restrict__ bf,
                                         const float* __restrict__ v,
                                         const int h) {
#pragma unroll
  for (int i = 0; i < 16; ++i) {
    const float mine = v[i];
    const float other = __shfl_xor(mine, 32);
    bf[i]      = h ? other : mine;
    bf[i + 16] = h ? mine  : other;
  }
}

__global__ __launch_bounds__(64) void logm_fc_kernel(const float* __restrict__ Qt,
                                                     const float* __restrict__ fcw,
                                                     const float* __restrict__ fcb,
                                                     float* __restrict__ out) {
  const int b = blockIdx.x;
  const int l = threadIdx.x;
  const int j = l & 31;
  const int h = l >> 5;
  const int r0 = h << 4;
  const bool hd = ((j >> 4) == h);
  const int id = j & 15;

  __shared__ float P[6][32][36];   // P[p] = t^(p+1)
  __shared__ float a_sh[44];       // Taylor coeffs a_0..a_41
  __shared__ float tl[32];         // combined t = W21*(s1+s2)

  const float* Qb1 = Qt + (size_t)(2 * b) * 1056;
  const float* Qb2 = Qb1 + 1056;

  if (l < 42) {
    if (l == 0) a_sh[0] = logf(M0);
    else a_sh[l] = ((l & 1) ? 1.f : -1.f) * __powf(BETA, (float)l) / (float)l;
  }
  if (l < 32) tl[l] = Qb1[1024 + l] + Qb2[1024 + l];
  __syncthreads();

  float cur[16], nxt[16], acc[16], bf[32];
  const float invT = 1.f / TN;
  const float sc1 = (1.f / (TN - 1)) * (1.f / R0);
  const float DIAGC = (SPD_EPS - M0) / R0;
  const float tj = tl[j];
#pragma unroll
  for (int i = 0; i < 16; ++i) {
    const int row = r0 + i;
    const float q = Qb1[row * 32 + j] + Qb2[row * 32 + j];
    float v = (q - tl[row] * tj * invT) * sc1;
    if (hd && i == id) v += DIAGC;
    cur[i] = v;
    P[0][r0 + i][j] = v;
  }
  __syncthreads();

  // powers t^2..t^6; unroll 1 so the invariant A operand isn't register-cached
#pragma unroll 1
  for (int p = 1; p < 6; ++p) {
    expand32(bf, cur, h);
    mm_half(nxt, P[0], bf, r0);
#pragma unroll
    for (int i = 0; i < 16; ++i) { cur[i] = nxt[i]; P[p][r0 + i][j] = nxt[i]; }
  }
  __syncthreads();   // powers + coeffs visible

  // ACC = B_6 = a36 I + sum_{p=1..5} a_{36+p} t^p
#pragma unroll
  for (int i = 0; i < 16; ++i) {
    float v = (hd && i == id) ? a_sh[36] : 0.f;
#pragma unroll
    for (int p = 0; p < 5; ++p)
      v = fmaf(a_sh[37 + p], P[p][r0 + i][j], v);
    acc[i] = v;
  }
  // Horner: ACC = u*ACC + B_jj, u = t^6 (LDS, never rewritten); unroll 1
#pragma unroll 1
  for (int jj = 5; jj >= 0; --jj) {
    expand32(bf, acc, h);
    mm_half(nxt, P[5], bf, r0);
#pragma unroll
    for (int i = 0; i < 16; ++i) {
      float v = (hd && i == id) ? a_sh[6 * jj] : 0.f;
#pragma unroll
      for (int p = 0; p < 5; ++p)
        v = fmaf(a_sh[6 * jj + 1 + p], P[p][r0 + i][j], v);
      acc[i] = v + nxt[i];
    }
  }

  // fused FC: out[b][k] = fcb[k] + sum_{r,c} L[r][c] * fcw[k][r*32+c]
#pragma unroll 2
  for (int k = 0; k < 10; ++k) {
    const float* fw = fcw + (size_t)k * 1024;
    float s = 0.f;
#pragma unroll
    for (int i = 0; i < 16; ++i)
      s = fmaf(acc[i], fw[(r0 + i) * 32 + j], s);
#pragma unroll
    for (int d = 1; d < 64; d <<= 1) s += __shfl_xor(s, d);
    if (l == 0) out[b * 10 + k] = s + fcb[k];
  }
}

extern "C" void kernel_launch(void* const* d_in, const int* in_sizes, int n_in,
                              void* d_out, int out_size, void* d_ws, size_t ws_size,
                              hipStream_t stream) {
  const float* x   = (const float*)d_in[0];
  const float* W1  = (const float*)d_in[1];
  const float* W2  = (const float*)d_in[2];
  const float* fcw = (const float*)d_in[3];
  const float* fcb = (const float*)d_in[4];
  float* out = (float*)d_out;
  char* ws = (char*)d_ws;
  float* W21 = (float*)ws;              // 16 KB
  float* Qt  = (float*)(ws + 65536);    // 1024 * 1056 * 4 = 4.3 MB

  w21_kernel<<<16, 256, 0, stream>>>(W2, W1, W21);
  cov_kernel<<<1024, 256, 0, stream>>>(x, W21, Qt);
  logm_fc_kernel<<<512, 64, 0, stream>>>(Qt, fcw, fcb, out);
}